// Round 3
// baseline (884.966 us; speedup 1.0000x reference)
//
#include <hip/hip_runtime.h>
#include <hip/hip_bf16.h>

#define BB 2
#define NN 20000
#define EE 200000
#define INF 256
#define OUTF 32
#define NH 4
#define HF 128          // NH*OUTF
#define NEG_SLOPE 0.2f

using bf16 = __hip_bfloat16;

__device__ __forceinline__ float bflo(unsigned u){ return __uint_as_float(u << 16); }
__device__ __forceinline__ float bfhi(unsigned u){ return __uint_as_float(u & 0xffff0000u); }
__device__ __forceinline__ float bf2f(unsigned short s){ return __uint_as_float((unsigned)s << 16); }

// flags[0] = 1 if x/W/a are fp32, 0 if bf16
// flags[1] = 1 if edge_indices are int64, 0 if int32
__global__ void k_detect(const ushort* __restrict__ xr, const int* __restrict__ er,
                         int* __restrict__ flags){
    __shared__ int cnt_big, cnt_nz;
    if (threadIdx.x == 0){ cnt_big = 0; cnt_nz = 0; }
    __syncthreads();
    int big = 0;
    for (int i = threadIdx.x; i < 8192; i += blockDim.x){
        unsigned short v = xr[2 * i];          // fp32 buffer: low mantissa half (uniform bits)
        unsigned e = (v >> 7) & 0xff;          // bf16-exponent field
        if (e >= 0xC0) big++;                  // |val| >= 2^65 — impossible for N(0,1) bf16
    }
    int nz = 0;
    for (int i = threadIdx.x; i < 4096; i += blockDim.x){
        if (er[2 * i + 1] != 0) nz++;          // int64 buffer: high words all zero
    }
    atomicAdd(&cnt_big, big);
    atomicAdd(&cnt_nz, nz);
    __syncthreads();
    if (threadIdx.x == 0){
        flags[0] = (cnt_big >= 16) ? 1 : 0;
        flags[1] = (cnt_nz == 0) ? 1 : 0;
    }
}

__device__ __forceinline__ int get_src(const int* ei, int e, int f64){
    return f64 ? ei[2 * e] : ei[e];
}
__device__ __forceinline__ int get_dst(const int* ei, int e, int f64){
    return f64 ? ei[2 * EE + 2 * e] : ei[EE + e];
}
__device__ __forceinline__ float loadh(const void* h, size_t idx, int hf32){
    return hf32 ? ((const float*)h)[idx] : __bfloat162float(((const bf16*)h)[idx]);
}

// K0: zero fp32 output accumulator (d_out), init last_edge to -1
__global__ void k_init(float* __restrict__ out_f, int* __restrict__ last_e){
    int i = blockIdx.x * blockDim.x + threadIdx.x;
    if (i < BB * NN * OUTF) out_f[i] = 0.f;
    if (i < NN) last_e[i] = -1;
}

// K1: h[b,n,col] = sum_k x[b,n,k] * W[col,k]
__global__ void k_gemm(const void* __restrict__ xv, const void* __restrict__ Wv,
                       const int* __restrict__ flags, void* __restrict__ h, int hf32){
    int t = blockIdx.x * blockDim.x + threadIdx.x;
    if (t >= BB * NN * HF) return;
    int col = t & (HF - 1);
    int row = t >> 7;
    float acc = 0.f;
    if (flags[0]){               // fp32 inputs
        const float4* xp = (const float4*)((const float*)xv + (size_t)row * INF);
        const float4* wp = (const float4*)((const float*)Wv + (size_t)col * INF);
        #pragma unroll 8
        for (int k = 0; k < INF / 4; ++k){
            float4 a = xp[k], b = wp[k];
            acc += a.x * b.x + a.y * b.y + a.z * b.z + a.w * b.w;
        }
    } else {                     // bf16 inputs
        const uint4* xp = (const uint4*)((const ushort*)xv + (size_t)row * INF);
        const uint4* wp = (const uint4*)((const ushort*)Wv + (size_t)col * INF);
        #pragma unroll 4
        for (int k = 0; k < INF / 8; ++k){
            uint4 a = xp[k], b = wp[k];
            acc += bflo(a.x) * bflo(b.x) + bfhi(a.x) * bfhi(b.x);
            acc += bflo(a.y) * bflo(b.y) + bfhi(a.y) * bfhi(b.y);
            acc += bflo(a.z) * bflo(b.z) + bfhi(a.z) * bfhi(b.z);
            acc += bflo(a.w) * bflo(b.w) + bfhi(a.w) * bfhi(b.w);
        }
    }
    if (hf32) ((float*)h)[t] = acc;
    else      ((bf16*)h)[t]  = __float2bfloat16(acc);
}

// K2: per (b,n,head) dot of h with a_src / a_dst
__global__ void k_alpha(const void* __restrict__ h, const void* __restrict__ av,
                        const int* __restrict__ flags, int hf32,
                        float* __restrict__ alpha_s, float* __restrict__ alpha_d){
    int t = blockIdx.x * blockDim.x + threadIdx.x;     // B*N*NH
    if (t >= BB * NN * NH) return;
    int hd = t & 3;
    int bn = t >> 2;
    size_t base = (size_t)bn * HF + hd * OUTF;
    bool f32in = flags[0] != 0;
    const float*  af = (const float*)av;
    const ushort* ab = (const ushort*)av;
    float as = 0.f, ad = 0.f;
    #pragma unroll
    for (int f = 0; f < OUTF; ++f){
        float v  = loadh(h, base + f, hf32);
        float cs = f32in ? af[f]        : bf2f(ab[f]);
        float cd = f32in ? af[OUTF + f] : bf2f(ab[OUTF + f]);
        as += v * cs;
        ad += v * cd;
    }
    alpha_s[t] = as;
    alpha_d[t] = ad;
}

// K3: last edge id per source node
__global__ void k_lastedge(const int* __restrict__ ei, const int* __restrict__ flags,
                           int* __restrict__ last_e){
    int e = blockIdx.x * blockDim.x + threadIdx.x;
    if (e < EE) atomicMax(&last_e[get_src(ei, e, flags[1])], e);
}

// K4: attention weight per (b,node,head): batch softmax at last edge, /NH folded in
__global__ void k_aw(const int* __restrict__ ei, const int* __restrict__ flags,
                     const int* __restrict__ last_e,
                     const float* __restrict__ alpha_s, const float* __restrict__ alpha_d,
                     float* __restrict__ aw){
    int n = blockIdx.x * blockDim.x + threadIdx.x;
    if (n >= NN) return;
    int le = last_e[n];
    if (le < 0){
        #pragma unroll
        for (int hh = 0; hh < NH; ++hh){
            aw[((size_t)0 * NN + n) * NH + hh] = 0.f;
            aw[((size_t)1 * NN + n) * NH + hh] = 0.f;
        }
        return;
    }
    int d = get_dst(ei, le, flags[1]);
    #pragma unroll
    for (int hh = 0; hh < NH; ++hh){
        float s0 = alpha_s[((size_t)0 * NN + n) * NH + hh] + alpha_d[((size_t)0 * NN + d) * NH + hh];
        float s1 = alpha_s[((size_t)1 * NN + n) * NH + hh] + alpha_d[((size_t)1 * NN + d) * NH + hh];
        s0 = s0 > 0.f ? s0 : NEG_SLOPE * s0;
        s1 = s1 > 0.f ? s1 : NEG_SLOPE * s1;
        float m  = fmaxf(s0, s1);
        float e0 = __expf(s0 - m);
        float e1 = __expf(s1 - m);
        float inv = 1.f / (e0 + e1);
        aw[((size_t)0 * NN + n) * NH + hh] = 0.25f * e0 * inv;
        aw[((size_t)1 * NN + n) * NH + hh] = 0.25f * e1 * inv;
    }
}

// K5: edge scatter directly into fp32 d_out. One wave per edge; lane = b*32+f.
//     out[b,src,f] += sum_h aw[b,src,h] * h[b,dst,h*32+f]
__global__ void k_scatter(const int* __restrict__ ei, const int* __restrict__ flags,
                          const void* __restrict__ h, int hf32,
                          const float* __restrict__ aw, float* __restrict__ out_f){
    int lane = threadIdx.x & 63;
    int wid  = (blockIdx.x * blockDim.x + threadIdx.x) >> 6;
    int nw   = (gridDim.x * blockDim.x) >> 6;
    int b = lane >> 5;
    int f = lane & 31;
    int f64 = flags[1];
    for (int e = wid; e < EE; e += nw){
        int s = get_src(ei, e, f64);
        int d = get_dst(ei, e, f64);
        const float4 awv = *(const float4*)(aw + ((size_t)b * NN + s) * NH);
        size_t hb = ((size_t)b * NN + d) * HF + f;
        float acc = awv.x * loadh(h, hb,      hf32)
                  + awv.y * loadh(h, hb + 32, hf32)
                  + awv.z * loadh(h, hb + 64, hf32)
                  + awv.w * loadh(h, hb + 96, hf32);
        atomicAdd(&out_f[((size_t)b * NN + s) * OUTF + f], acc);
    }
}

extern "C" void kernel_launch(void* const* d_in, const int* in_sizes, int n_in,
                              void* d_out, int out_size, void* d_ws, size_t ws_size,
                              hipStream_t stream){
    // Resolve inputs by flat element count (paranoia vs ordering assumptions).
    const void* x = d_in[0]; const void* eiv = d_in[1];
    const void* W = d_in[2]; const void* a  = d_in[3];
    for (int i = 0; i < n_in; ++i){
        if      (in_sizes[i] == BB * NN * INF) x   = d_in[i];
        else if (in_sizes[i] == 2 * EE)        eiv = d_in[i];
        else if (in_sizes[i] == HF * INF)      W   = d_in[i];
        else if (in_sizes[i] == 2 * OUTF)      a   = d_in[i];
    }
    const int* ei = (const int*)eiv;
    float* out = (float*)d_out;    // reference output dtype: float32

    // Workspace: flags | h | alpha_s | alpha_d | aw | last_e
    const size_t HN = (size_t)BB * NN * HF;
    int hf32 = (ws_size >= 64 + HN * 4 + 3 * (size_t)BB * NN * NH * 4 + NN * 4 + 1024) ? 1 : 0;
    char* p = (char*)d_ws;
    int*   flags   = (int*)p;                         p += 64;
    void*  h       = (void*)p;                        p += HN * (hf32 ? 4 : 2);
    float* alpha_s = (float*)p;                       p += (size_t)BB * NN * NH * 4;
    float* alpha_d = (float*)p;                       p += (size_t)BB * NN * NH * 4;
    float* aw      = (float*)p;                       p += (size_t)BB * NN * NH * 4;
    int*   last_e  = (int*)p;

    k_detect  <<<1, 256, 0, stream>>>((const ushort*)x, ei, flags);
    k_init    <<<(BB * NN * OUTF + 255) / 256, 256, 0, stream>>>(out, last_e);
    k_gemm    <<<(BB * NN * HF + 255) / 256, 256, 0, stream>>>(x, W, flags, h, hf32);
    k_alpha   <<<(BB * NN * NH + 255) / 256, 256, 0, stream>>>(h, a, flags, hf32, alpha_s, alpha_d);
    k_lastedge<<<(EE + 255) / 256, 256, 0, stream>>>(ei, flags, last_e);
    k_aw      <<<(NN + 255) / 256, 256, 0, stream>>>(ei, flags, last_e, alpha_s, alpha_d, aw);
    k_scatter <<<2048, 256, 0, stream>>>(ei, flags, h, hf32, aw, out);
}

// Round 4
// 329.436 us; speedup vs baseline: 2.6863x; 2.6863x over previous
//
#include <hip/hip_runtime.h>
#include <hip/hip_bf16.h>

#define BB 2
#define NN 20000
#define EE 200000
#define INF 256
#define OUTF 32
#define NH 4
#define HF 128          // NH*OUTF
#define NEG_SLOPE 0.2f

using bf16 = __hip_bfloat16;

__device__ __forceinline__ float bflo(unsigned u){ return __uint_as_float(u << 16); }
__device__ __forceinline__ float bfhi(unsigned u){ return __uint_as_float(u & 0xffff0000u); }
__device__ __forceinline__ float bf2f(unsigned short s){ return __uint_as_float((unsigned)s << 16); }

// flags[0] = 1 if x/W/a are fp32, 0 if bf16   (measured round 1-3: fp32)
// flags[1] = 1 if edge_indices are int64, 0 if int32
__global__ void k_detect(const ushort* __restrict__ xr, const int* __restrict__ er,
                         int* __restrict__ flags){
    __shared__ int cnt_big, cnt_nz;
    if (threadIdx.x == 0){ cnt_big = 0; cnt_nz = 0; }
    __syncthreads();
    int big = 0;
    for (int i = threadIdx.x; i < 8192; i += blockDim.x){
        unsigned short v = xr[2 * i];
        unsigned e = (v >> 7) & 0xff;
        if (e >= 0xC0) big++;
    }
    int nz = 0;
    for (int i = threadIdx.x; i < 4096; i += blockDim.x){
        if (er[2 * i + 1] != 0) nz++;
    }
    atomicAdd(&cnt_big, big);
    atomicAdd(&cnt_nz, nz);
    __syncthreads();
    if (threadIdx.x == 0){
        flags[0] = (cnt_big >= 16) ? 1 : 0;
        flags[1] = (cnt_nz == 0) ? 1 : 0;
    }
}

__device__ __forceinline__ int get_src(const int* ei, int e, int f64){
    return f64 ? ei[2 * e] : ei[e];
}
__device__ __forceinline__ int get_dst(const int* ei, int e, int f64){
    return f64 ? ei[2 * EE + 2 * e] : ei[EE + e];
}
__device__ __forceinline__ float loadh(const void* h, size_t idx, int hf32){
    return hf32 ? ((const float*)h)[idx] : __bfloat162float(((const bf16*)h)[idx]);
}

// K0: zero fp32 output (d_out), init last_edge to -1
__global__ void k_init(float* __restrict__ out_f, int* __restrict__ last_e){
    int i = blockIdx.x * blockDim.x + threadIdx.x;
    if (i < BB * NN * OUTF) out_f[i] = 0.f;
    if (i < NN) last_e[i] = -1;
}

// K1 v2: LDS-tiled GEMM. Grid = 512 blocks; block = (col-half, row-stripe).
// LDS holds 64 cols x 256 K of W (fp32, 64 KB) with (k + 4*col)&255 rotation
// so compute-phase ds_read_b128 is bank-balanced. lane = col (coalesced h
// stores), wave = 8 rows (x loads wave-uniform -> broadcast). 2 blocks/CU.
__global__ __launch_bounds__(512, 4)
void k_gemm2(const void* __restrict__ xv_, const void* __restrict__ Wv,
             const int* __restrict__ flags, void* __restrict__ h, int hf32){
    __shared__ float Wl[64 * 256];   // exactly 64 KB
    const int tid = threadIdx.x;
    const int colbase = (blockIdx.x & 1) * 64;
    const bool f32 = flags[0] != 0;

    // ---- stage W half (global coalesced read, swizzled LDS write) ----
    if (f32){
        const float* Wg = (const float*)Wv;
        for (int idx = tid; idx < 4096; idx += 512){
            int c = idx >> 6, m = idx & 63;                 // k = 4m
            float4 v = *(const float4*)(Wg + ((size_t)(colbase + c)) * INF + 4 * m);
            int kk = (4 * m + 4 * c) & 255;
            *(float4*)&Wl[c * 256 + kk] = v;
        }
    } else {
        const ushort* Wg = (const ushort*)Wv;
        for (int idx = tid; idx < 4096; idx += 512){
            int c = idx >> 6, m = idx & 63;
            const ushort4 u = *(const ushort4*)(Wg + ((size_t)(colbase + c)) * INF + 4 * m);
            float4 v = make_float4(bf2f(u.x), bf2f(u.y), bf2f(u.z), bf2f(u.w));
            int kk = (4 * m + 4 * c) & 255;
            *(float4*)&Wl[c * 256 + kk] = v;
        }
    }
    __syncthreads();

    const int lane = tid & 63;       // col within half
    const int wvid = tid >> 6;       // wave id 0..7 -> 8 rows each
    const float* lp = &Wl[lane * 256];

    for (int rc = (int)(blockIdx.x >> 1); rc < 625; rc += 256){
        int row0 = rc * 64 + wvid * 8;
        float acc[8];
        #pragma unroll
        for (int r = 0; r < 8; ++r) acc[r] = 0.f;

        if (f32){
            const float* xrow = (const float*)xv_ + (size_t)row0 * INF;
            #pragma unroll 4
            for (int k4 = 0; k4 < 256; k4 += 4){
                float4 w = *(const float4*)&lp[(k4 + 4 * lane) & 255];
                #pragma unroll
                for (int r = 0; r < 8; ++r){
                    float4 xv = *(const float4*)&xrow[(size_t)r * INF + k4];
                    acc[r] += w.x * xv.x + w.y * xv.y + w.z * xv.z + w.w * xv.w;
                }
            }
        } else {
            const ushort* xrow = (const ushort*)xv_ + (size_t)row0 * INF;
            #pragma unroll 4
            for (int k4 = 0; k4 < 256; k4 += 4){
                float4 w = *(const float4*)&lp[(k4 + 4 * lane) & 255];
                #pragma unroll
                for (int r = 0; r < 8; ++r){
                    ushort4 u = *(const ushort4*)&xrow[(size_t)r * INF + k4];
                    acc[r] += w.x * bf2f(u.x) + w.y * bf2f(u.y)
                            + w.z * bf2f(u.z) + w.w * bf2f(u.w);
                }
            }
        }

        #pragma unroll
        for (int r = 0; r < 8; ++r){
            size_t o = (size_t)(row0 + r) * HF + colbase + lane;
            if (hf32) ((float*)h)[o] = acc[r];
            else      ((bf16*)h)[o]  = __float2bfloat16(acc[r]);
        }
    }
}

// K2: per (b,n,head) dot of h with a_src / a_dst
__global__ void k_alpha(const void* __restrict__ h, const void* __restrict__ av,
                        const int* __restrict__ flags, int hf32,
                        float* __restrict__ alpha_s, float* __restrict__ alpha_d){
    int t = blockIdx.x * blockDim.x + threadIdx.x;
    if (t >= BB * NN * NH) return;
    int hd = t & 3;
    int bn = t >> 2;
    size_t base = (size_t)bn * HF + hd * OUTF;
    bool f32in = flags[0] != 0;
    const float*  af = (const float*)av;
    const ushort* ab = (const ushort*)av;
    float as = 0.f, ad = 0.f;
    #pragma unroll
    for (int f = 0; f < OUTF; ++f){
        float v  = loadh(h, base + f, hf32);
        float cs = f32in ? af[f]        : bf2f(ab[f]);
        float cd = f32in ? af[OUTF + f] : bf2f(ab[OUTF + f]);
        as += v * cs;
        ad += v * cd;
    }
    alpha_s[t] = as;
    alpha_d[t] = ad;
}

// K3: last edge id per source node
__global__ void k_lastedge(const int* __restrict__ ei, const int* __restrict__ flags,
                           int* __restrict__ last_e){
    int e = blockIdx.x * blockDim.x + threadIdx.x;
    if (e < EE) atomicMax(&last_e[get_src(ei, e, flags[1])], e);
}

// K4: attention weight per (b,node,head): batch softmax at last edge, /NH folded in
__global__ void k_aw(const int* __restrict__ ei, const int* __restrict__ flags,
                     const int* __restrict__ last_e,
                     const float* __restrict__ alpha_s, const float* __restrict__ alpha_d,
                     float* __restrict__ aw){
    int n = blockIdx.x * blockDim.x + threadIdx.x;
    if (n >= NN) return;
    int le = last_e[n];
    if (le < 0){
        #pragma unroll
        for (int hh = 0; hh < NH; ++hh){
            aw[((size_t)0 * NN + n) * NH + hh] = 0.f;
            aw[((size_t)1 * NN + n) * NH + hh] = 0.f;
        }
        return;
    }
    int d = get_dst(ei, le, flags[1]);
    #pragma unroll
    for (int hh = 0; hh < NH; ++hh){
        float s0 = alpha_s[((size_t)0 * NN + n) * NH + hh] + alpha_d[((size_t)0 * NN + d) * NH + hh];
        float s1 = alpha_s[((size_t)1 * NN + n) * NH + hh] + alpha_d[((size_t)1 * NN + d) * NH + hh];
        s0 = s0 > 0.f ? s0 : NEG_SLOPE * s0;
        s1 = s1 > 0.f ? s1 : NEG_SLOPE * s1;
        float m  = fmaxf(s0, s1);
        float e0 = __expf(s0 - m);
        float e1 = __expf(s1 - m);
        float inv = 1.f / (e0 + e1);
        aw[((size_t)0 * NN + n) * NH + hh] = 0.25f * e0 * inv;
        aw[((size_t)1 * NN + n) * NH + hh] = 0.25f * e1 * inv;
    }
}

// K5: edge scatter into fp32 d_out. One wave per edge; lane = b*32+f.
__global__ void k_scatter(const int* __restrict__ ei, const int* __restrict__ flags,
                          const void* __restrict__ h, int hf32,
                          const float* __restrict__ aw, float* __restrict__ out_f){
    int lane = threadIdx.x & 63;
    int wid  = (blockIdx.x * blockDim.x + threadIdx.x) >> 6;
    int nw   = (gridDim.x * blockDim.x) >> 6;
    int b = lane >> 5;
    int f = lane & 31;
    int f64 = flags[1];
    for (int e = wid; e < EE; e += nw){
        int s = get_src(ei, e, f64);
        int d = get_dst(ei, e, f64);
        const float4 awv = *(const float4*)(aw + ((size_t)b * NN + s) * NH);
        size_t hb = ((size_t)b * NN + d) * HF + f;
        float acc = awv.x * loadh(h, hb,      hf32)
                  + awv.y * loadh(h, hb + 32, hf32)
                  + awv.z * loadh(h, hb + 64, hf32)
                  + awv.w * loadh(h, hb + 96, hf32);
        atomicAdd(&out_f[((size_t)b * NN + s) * OUTF + f], acc);
    }
}

extern "C" void kernel_launch(void* const* d_in, const int* in_sizes, int n_in,
                              void* d_out, int out_size, void* d_ws, size_t ws_size,
                              hipStream_t stream){
    const void* x = d_in[0]; const void* eiv = d_in[1];
    const void* W = d_in[2]; const void* a  = d_in[3];
    for (int i = 0; i < n_in; ++i){
        if      (in_sizes[i] == BB * NN * INF) x   = d_in[i];
        else if (in_sizes[i] == 2 * EE)        eiv = d_in[i];
        else if (in_sizes[i] == HF * INF)      W   = d_in[i];
        else if (in_sizes[i] == 2 * OUTF)      a   = d_in[i];
    }
    const int* ei = (const int*)eiv;
    float* out = (float*)d_out;    // output dtype: float32 (verified round 3)

    const size_t HN = (size_t)BB * NN * HF;
    int hf32 = (ws_size >= 64 + HN * 4 + 3 * (size_t)BB * NN * NH * 4 + NN * 4 + 1024) ? 1 : 0;
    char* p = (char*)d_ws;
    int*   flags   = (int*)p;                         p += 64;
    void*  h       = (void*)p;                        p += HN * (hf32 ? 4 : 2);
    float* alpha_s = (float*)p;                       p += (size_t)BB * NN * NH * 4;
    float* alpha_d = (float*)p;                       p += (size_t)BB * NN * NH * 4;
    float* aw      = (float*)p;                       p += (size_t)BB * NN * NH * 4;
    int*   last_e  = (int*)p;

    k_detect  <<<1, 256, 0, stream>>>((const ushort*)x, ei, flags);
    k_init    <<<(BB * NN * OUTF + 255) / 256, 256, 0, stream>>>(out, last_e);
    k_gemm2   <<<512, 512, 0, stream>>>(x, W, flags, h, hf32);
    k_alpha   <<<(BB * NN * NH + 255) / 256, 256, 0, stream>>>(h, a, flags, hf32, alpha_s, alpha_d);
    k_lastedge<<<(EE + 255) / 256, 256, 0, stream>>>(ei, flags, last_e);
    k_aw      <<<(NN + 255) / 256, 256, 0, stream>>>(ei, flags, last_e, alpha_s, alpha_d, aw);
    k_scatter <<<2048, 256, 0, stream>>>(ei, flags, h, hf32, aw, out);
}

// Round 5
// 210.032 us; speedup vs baseline: 4.2135x; 1.5685x over previous
//
#include <hip/hip_runtime.h>
#include <hip/hip_bf16.h>

#define BB 2
#define NN 20000
#define EE 200000
#define INF 256
#define OUTF 32
#define NH 4
#define HF 128          // NH*OUTF
#define NEG_SLOPE 0.2f

using bf16 = __hip_bfloat16;

__device__ __forceinline__ float bf2f(unsigned short s){ return __uint_as_float((unsigned)s << 16); }

__device__ __forceinline__ int get_src(const int* ei, int e, int f64){
    return f64 ? ei[2 * e] : ei[e];
}
__device__ __forceinline__ int get_dst(const int* ei, int e, int f64){
    return f64 ? ei[2 * EE + 2 * e] : ei[EE + e];
}
__device__ __forceinline__ float loadh(const void* h, size_t idx, int hf32){
    return hf32 ? ((const float*)h)[idx] : __bfloat162float(((const bf16*)h)[idx]);
}

// K0: zero fp32 output (d_out), init last_edge, and (block 0) dtype-detect.
// flags[0]=1 if x fp32 (measured: fp32), flags[1]=1 if edge idx int64.
__global__ void k_init(const ushort* __restrict__ xr, const int* __restrict__ er,
                       int* __restrict__ flags, float* __restrict__ out_f,
                       int* __restrict__ last_e){
    int i = blockIdx.x * blockDim.x + threadIdx.x;
    if (i < BB * NN * OUTF) out_f[i] = 0.f;
    if (i < NN) last_e[i] = -1;
    if (blockIdx.x == 0){
        __shared__ int cnt_big, cnt_nz;
        if (threadIdx.x == 0){ cnt_big = 0; cnt_nz = 0; }
        __syncthreads();
        int big = 0;
        for (int k = threadIdx.x; k < 8192; k += blockDim.x){
            unsigned e = ((unsigned)xr[2 * k] >> 7) & 0xff;   // bf16-exponent of fp32 low half
            if (e >= 0xC0) big++;                              // impossible for N(0,1) bf16
        }
        int nz = 0;
        for (int k = threadIdx.x; k < 4096; k += blockDim.x){
            if (er[2 * k + 1] != 0) nz++;                      // int64 high words all zero
        }
        atomicAdd(&cnt_big, big);
        atomicAdd(&cnt_nz, nz);
        __syncthreads();
        if (threadIdx.x == 0){
            flags[0] = (cnt_big >= 16) ? 1 : 0;
            flags[1] = (cnt_nz == 0) ? 1 : 0;
        }
    }
}

// K1 v3: double-LDS-tiled GEMM. Block = 64 rows x 128 cols, 256 threads,
// per-thread 8x4 micro-tile, K in 4 tiles of 64. x staged transposed [k][r]
// (a-frag = broadcast ds_read_b128), W staged transposed [k][c].
__global__ __launch_bounds__(256, 3)
void k_gemm3(const void* __restrict__ xv_, const void* __restrict__ Wv,
             const int* __restrict__ flags, void* __restrict__ h, int hf32){
    __shared__ float xs[64 * 64];     // [k][r]  16 KB
    __shared__ float ws[64 * 128];    // [k][c]  32 KB
    const int tid  = threadIdx.x;
    const int row0 = blockIdx.x * 64;
    const bool f32 = flags[0] != 0;
    const int c0 = (tid & 31) * 4;
    const int r0 = (tid >> 5) * 8;

    float4 acc[8];
    #pragma unroll
    for (int r = 0; r < 8; ++r) acc[r] = make_float4(0.f, 0.f, 0.f, 0.f);

    for (int kt = 0; kt < INF; kt += 64){
        __syncthreads();
        // ---- stage x tile: 64 rows x 64 k, transposed ----
        {
            int r = tid >> 2, kq = (tid & 3) * 4;
            if (f32){
                const float* xg = (const float*)xv_ + (size_t)(row0 + r) * INF + kt + kq;
                #pragma unroll
                for (int j = 0; j < 4; ++j){
                    float4 v = *(const float4*)(xg + 16 * j);
                    int kl = kq + 16 * j;
                    xs[(kl    ) * 64 + r] = v.x;
                    xs[(kl + 1) * 64 + r] = v.y;
                    xs[(kl + 2) * 64 + r] = v.z;
                    xs[(kl + 3) * 64 + r] = v.w;
                }
            } else {
                const ushort* xg = (const ushort*)xv_ + (size_t)(row0 + r) * INF + kt + kq;
                #pragma unroll
                for (int j = 0; j < 4; ++j){
                    ushort4 u = *(const ushort4*)(xg + 16 * j);
                    int kl = kq + 16 * j;
                    xs[(kl    ) * 64 + r] = bf2f(u.x);
                    xs[(kl + 1) * 64 + r] = bf2f(u.y);
                    xs[(kl + 2) * 64 + r] = bf2f(u.z);
                    xs[(kl + 3) * 64 + r] = bf2f(u.w);
                }
            }
        }
        // ---- stage W tile: 128 cols x 64 k, transposed ----
        {
            int c = tid >> 1, kh = (tid & 1) * 4;
            if (f32){
                const float* wg = (const float*)Wv + (size_t)c * INF + kt + kh;
                #pragma unroll
                for (int j = 0; j < 8; ++j){
                    float4 v = *(const float4*)(wg + 8 * j);
                    int kl = kh + 8 * j;
                    ws[(kl    ) * 128 + c] = v.x;
                    ws[(kl + 1) * 128 + c] = v.y;
                    ws[(kl + 2) * 128 + c] = v.z;
                    ws[(kl + 3) * 128 + c] = v.w;
                }
            } else {
                const ushort* wg = (const ushort*)Wv + (size_t)c * INF + kt + kh;
                #pragma unroll
                for (int j = 0; j < 8; ++j){
                    ushort4 u = *(const ushort4*)(wg + 8 * j);
                    int kl = kh + 8 * j;
                    ws[(kl    ) * 128 + c] = bf2f(u.x);
                    ws[(kl + 1) * 128 + c] = bf2f(u.y);
                    ws[(kl + 2) * 128 + c] = bf2f(u.z);
                    ws[(kl + 3) * 128 + c] = bf2f(u.w);
                }
            }
        }
        __syncthreads();
        // ---- compute 64 k-steps ----
        #pragma unroll 8
        for (int k = 0; k < 64; ++k){
            float4 b  = *(const float4*)&ws[k * 128 + c0];
            float4 a0 = *(const float4*)&xs[k * 64 + r0];
            float4 a1 = *(const float4*)&xs[k * 64 + r0 + 4];
            float ar[8] = {a0.x, a0.y, a0.z, a0.w, a1.x, a1.y, a1.z, a1.w};
            #pragma unroll
            for (int r = 0; r < 8; ++r){
                acc[r].x += ar[r] * b.x;
                acc[r].y += ar[r] * b.y;
                acc[r].z += ar[r] * b.z;
                acc[r].w += ar[r] * b.w;
            }
        }
    }
    // ---- epilogue ----
    #pragma unroll
    for (int r = 0; r < 8; ++r){
        size_t o = (size_t)(row0 + r0 + r) * HF + c0;
        if (hf32){
            *(float4*)((float*)h + o) = acc[r];
        } else {
            bf16* hp = (bf16*)h + o;
            hp[0] = __float2bfloat16(acc[r].x);
            hp[1] = __float2bfloat16(acc[r].y);
            hp[2] = __float2bfloat16(acc[r].z);
            hp[3] = __float2bfloat16(acc[r].w);
        }
    }
}

// K2: per (b,n,head) dot of h with a_src / a_dst
__global__ void k_alpha(const void* __restrict__ h, const void* __restrict__ av,
                        const int* __restrict__ flags, int hf32,
                        float* __restrict__ alpha_s, float* __restrict__ alpha_d){
    int t = blockIdx.x * blockDim.x + threadIdx.x;
    if (t >= BB * NN * NH) return;
    int hd = t & 3;
    int bn = t >> 2;
    size_t base = (size_t)bn * HF + hd * OUTF;
    bool f32in = flags[0] != 0;
    const float*  af = (const float*)av;
    const ushort* ab = (const ushort*)av;
    float as = 0.f, ad = 0.f;
    #pragma unroll
    for (int f = 0; f < OUTF; ++f){
        float v  = loadh(h, base + f, hf32);
        float cs = f32in ? af[f]        : bf2f(ab[f]);
        float cd = f32in ? af[OUTF + f] : bf2f(ab[OUTF + f]);
        as += v * cs;
        ad += v * cd;
    }
    alpha_s[t] = as;
    alpha_d[t] = ad;
}

// K3: last edge id per source node
__global__ void k_lastedge(const int* __restrict__ ei, const int* __restrict__ flags,
                           int* __restrict__ last_e){
    int e = blockIdx.x * blockDim.x + threadIdx.x;
    if (e < EE) atomicMax(&last_e[get_src(ei, e, flags[1])], e);
}

// K4: attention weight per (b,node,head): batch softmax at last edge, /NH folded in
__global__ void k_aw(const int* __restrict__ ei, const int* __restrict__ flags,
                     const int* __restrict__ last_e,
                     const float* __restrict__ alpha_s, const float* __restrict__ alpha_d,
                     float* __restrict__ aw){
    int n = blockIdx.x * blockDim.x + threadIdx.x;
    if (n >= NN) return;
    int le = last_e[n];
    if (le < 0){
        #pragma unroll
        for (int hh = 0; hh < NH; ++hh){
            aw[((size_t)0 * NN + n) * NH + hh] = 0.f;
            aw[((size_t)1 * NN + n) * NH + hh] = 0.f;
        }
        return;
    }
    int d = get_dst(ei, le, flags[1]);
    #pragma unroll
    for (int hh = 0; hh < NH; ++hh){
        float s0 = alpha_s[((size_t)0 * NN + n) * NH + hh] + alpha_d[((size_t)0 * NN + d) * NH + hh];
        float s1 = alpha_s[((size_t)1 * NN + n) * NH + hh] + alpha_d[((size_t)1 * NN + d) * NH + hh];
        s0 = s0 > 0.f ? s0 : NEG_SLOPE * s0;
        s1 = s1 > 0.f ? s1 : NEG_SLOPE * s1;
        float m  = fmaxf(s0, s1);
        float e0 = __expf(s0 - m);
        float e1 = __expf(s1 - m);
        float inv = 1.f / (e0 + e1);
        aw[((size_t)0 * NN + n) * NH + hh] = 0.25f * e0 * inv;
        aw[((size_t)1 * NN + n) * NH + hh] = 0.25f * e1 * inv;
    }
}

// K5: edge scatter into fp32 d_out. One wave per edge; lane = b*32+f.
__global__ void k_scatter(const int* __restrict__ ei, const int* __restrict__ flags,
                          const void* __restrict__ h, int hf32,
                          const float* __restrict__ aw, float* __restrict__ out_f){
    int lane = threadIdx.x & 63;
    int wid  = (blockIdx.x * blockDim.x + threadIdx.x) >> 6;
    int nw   = (gridDim.x * blockDim.x) >> 6;
    int b = lane >> 5;
    int f = lane & 31;
    int f64 = flags[1];
    for (int e = wid; e < EE; e += nw){
        int s = get_src(ei, e, f64);
        int d = get_dst(ei, e, f64);
        const float4 awv = *(const float4*)(aw + ((size_t)b * NN + s) * NH);
        size_t hb = ((size_t)b * NN + d) * HF + f;
        float acc = awv.x * loadh(h, hb,      hf32)
                  + awv.y * loadh(h, hb + 32, hf32)
                  + awv.z * loadh(h, hb + 64, hf32)
                  + awv.w * loadh(h, hb + 96, hf32);
        atomicAdd(&out_f[((size_t)b * NN + s) * OUTF + f], acc);
    }
}

extern "C" void kernel_launch(void* const* d_in, const int* in_sizes, int n_in,
                              void* d_out, int out_size, void* d_ws, size_t ws_size,
                              hipStream_t stream){
    const void* x = d_in[0]; const void* eiv = d_in[1];
    const void* W = d_in[2]; const void* a  = d_in[3];
    for (int i = 0; i < n_in; ++i){
        if      (in_sizes[i] == BB * NN * INF) x   = d_in[i];
        else if (in_sizes[i] == 2 * EE)        eiv = d_in[i];
        else if (in_sizes[i] == HF * INF)      W   = d_in[i];
        else if (in_sizes[i] == 2 * OUTF)      a   = d_in[i];
    }
    const int* ei = (const int*)eiv;
    float* out = (float*)d_out;    // output dtype: float32 (verified round 3)

    const size_t HN = (size_t)BB * NN * HF;
    int hf32 = (ws_size >= 64 + HN * 4 + 3 * (size_t)BB * NN * NH * 4 + NN * 4 + 1024) ? 1 : 0;
    char* p = (char*)d_ws;
    int*   flags   = (int*)p;                         p += 64;
    void*  h       = (void*)p;                        p += HN * (hf32 ? 4 : 2);
    float* alpha_s = (float*)p;                       p += (size_t)BB * NN * NH * 4;
    float* alpha_d = (float*)p;                       p += (size_t)BB * NN * NH * 4;
    float* aw      = (float*)p;                       p += (size_t)BB * NN * NH * 4;
    int*   last_e  = (int*)p;

    k_init    <<<(BB * NN * OUTF + 255) / 256, 256, 0, stream>>>((const ushort*)x, ei, flags, out, last_e);
    k_gemm3   <<<625, 256, 0, stream>>>(x, W, flags, h, hf32);
    k_alpha   <<<(BB * NN * NH + 255) / 256, 256, 0, stream>>>(h, a, flags, hf32, alpha_s, alpha_d);
    k_lastedge<<<(EE + 255) / 256, 256, 0, stream>>>(ei, flags, last_e);
    k_aw      <<<(NN + 255) / 256, 256, 0, stream>>>(ei, flags, last_e, alpha_s, alpha_d, aw);
    k_scatter <<<2048, 256, 0, stream>>>(ei, flags, h, hf32, aw, out);
}

// Round 7
// 182.793 us; speedup vs baseline: 4.8414x; 1.1490x over previous
//
#include <hip/hip_runtime.h>
#include <hip/hip_bf16.h>

#define BB 2
#define NN 20000
#define EE 200000
#define INF 256
#define OUTF 32
#define NH 4
#define HF 128          // NH*OUTF
#define NEG_SLOPE 0.2f
#define GEMM_BLOCKS 625 // 40000 rows / 64
#define EDGE_BLOCKS 98

using bf16 = __hip_bfloat16;

__device__ __forceinline__ float bf2f(unsigned short s){ return __uint_as_float((unsigned)s << 16); }
__device__ __forceinline__ ushort f2bf_bits(float f){
    __hip_bfloat16 b = __float2bfloat16(f);
    return *(ushort*)&b;
}

__device__ __forceinline__ int get_src(const int* ei, int e, int f64){
    return f64 ? ei[2 * e] : ei[e];
}
__device__ __forceinline__ int get_dst(const int* ei, int e, int f64){
    return f64 ? ei[2 * EE + 2 * e] : ei[EE + e];
}

// K0: zero fp32 output (d_out), init last_edge, and (block 0) dtype-detect.
// flags[0]=1 if x fp32 (measured rounds 1-5: fp32), flags[1]=1 if edge idx int64.
__global__ void k_init(const ushort* __restrict__ xr, const int* __restrict__ er,
                       int* __restrict__ flags, float* __restrict__ out_f,
                       int* __restrict__ last_e){
    int i = blockIdx.x * blockDim.x + threadIdx.x;
    if (i < BB * NN * OUTF) out_f[i] = 0.f;
    if (i < NN) last_e[i] = -1;
    if (blockIdx.x == 0){
        __shared__ int cnt_big, cnt_nz;
        if (threadIdx.x == 0){ cnt_big = 0; cnt_nz = 0; }
        __syncthreads();
        int big = 0;
        for (int k = threadIdx.x; k < 8192; k += blockDim.x){
            unsigned e = ((unsigned)xr[2 * k] >> 7) & 0xff;   // bf16-exponent of fp32 low half
            if (e >= 0xC0) big++;                              // impossible for N(0,1) bf16
        }
        int nz = 0;
        for (int k = threadIdx.x; k < 4096; k += blockDim.x){
            if (er[2 * k + 1] != 0) nz++;                      // int64 high words all zero
        }
        atomicAdd(&cnt_big, big);
        atomicAdd(&cnt_nz, nz);
        __syncthreads();
        if (threadIdx.x == 0){
            flags[0] = (cnt_big >= 16) ? 1 : 0;
            flags[1] = (cnt_nz == 0) ? 1 : 0;
        }
    }
}

// K1: fused GEMM (+alpha epilogue, bf16 h) and last-edge atomicMax.
// Blocks [0,625): 64 rows x 128 cols LDS-tiled gemm, 8x4 micro-tile/thread.
// Blocks [625,723): grid-stride atomicMax over edges (needs only flags from K0).
__global__ __launch_bounds__(256, 3)
void k_fused(const void* __restrict__ xv_, const void* __restrict__ Wv,
             const void* __restrict__ av, const int* __restrict__ ei,
             const int* __restrict__ flags, ushort* __restrict__ h,
             float* __restrict__ alpha_s, float* __restrict__ alpha_d,
             int* __restrict__ last_e){
    __shared__ float xs[64 * 64];     // [k][r]  16 KB
    __shared__ float ws[64 * 128];    // [k][c]  32 KB

    if (blockIdx.x >= GEMM_BLOCKS){
        int f64 = flags[1];
        int t = (blockIdx.x - GEMM_BLOCKS) * 256 + threadIdx.x;
        for (int e = t; e < EE; e += EDGE_BLOCKS * 256)
            atomicMax(&last_e[get_src(ei, e, f64)], e);
        return;
    }

    const int tid  = threadIdx.x;
    const int row0 = blockIdx.x * 64;
    const bool f32 = flags[0] != 0;
    const int c0 = (tid & 31) * 4;
    const int r0 = (tid >> 5) * 8;

    float4 acc[8];
    #pragma unroll
    for (int r = 0; r < 8; ++r) acc[r] = make_float4(0.f, 0.f, 0.f, 0.f);

    for (int kt = 0; kt < INF; kt += 64){
        __syncthreads();
        // ---- stage x tile: 64 rows x 64 k, transposed [k][r] ----
        {
            int r = tid >> 2, kq = (tid & 3) * 4;
            if (f32){
                const float* xg = (const float*)xv_ + (size_t)(row0 + r) * INF + kt + kq;
                #pragma unroll
                for (int j = 0; j < 4; ++j){
                    float4 v = *(const float4*)(xg + 16 * j);
                    int kl = kq + 16 * j;
                    xs[(kl    ) * 64 + r] = v.x;
                    xs[(kl + 1) * 64 + r] = v.y;
                    xs[(kl + 2) * 64 + r] = v.z;
                    xs[(kl + 3) * 64 + r] = v.w;
                }
            } else {
                const ushort* xg = (const ushort*)xv_ + (size_t)(row0 + r) * INF + kt + kq;
                #pragma unroll
                for (int j = 0; j < 4; ++j){
                    ushort4 u = *(const ushort4*)(xg + 16 * j);
                    int kl = kq + 16 * j;
                    xs[(kl    ) * 64 + r] = bf2f(u.x);
                    xs[(kl + 1) * 64 + r] = bf2f(u.y);
                    xs[(kl + 2) * 64 + r] = bf2f(u.z);
                    xs[(kl + 3) * 64 + r] = bf2f(u.w);
                }
            }
        }
        // ---- stage W tile: 128 cols x 64 k, transposed [k][c] ----
        {
            int c = tid >> 1, kh = (tid & 1) * 4;
            if (f32){
                const float* wg = (const float*)Wv + (size_t)c * INF + kt + kh;
                #pragma unroll
                for (int j = 0; j < 8; ++j){
                    float4 v = *(const float4*)(wg + 8 * j);
                    int kl = kh + 8 * j;
                    ws[(kl    ) * 128 + c] = v.x;
                    ws[(kl + 1) * 128 + c] = v.y;
                    ws[(kl + 2) * 128 + c] = v.z;
                    ws[(kl + 3) * 128 + c] = v.w;
                }
            } else {
                const ushort* wg = (const ushort*)Wv + (size_t)c * INF + kt + kh;
                #pragma unroll
                for (int j = 0; j < 8; ++j){
                    ushort4 u = *(const ushort4*)(wg + 8 * j);
                    int kl = kh + 8 * j;
                    ws[(kl    ) * 128 + c] = bf2f(u.x);
                    ws[(kl + 1) * 128 + c] = bf2f(u.y);
                    ws[(kl + 2) * 128 + c] = bf2f(u.z);
                    ws[(kl + 3) * 128 + c] = bf2f(u.w);
                }
            }
        }
        __syncthreads();
        // ---- compute 64 k-steps ----
        #pragma unroll 8
        for (int k = 0; k < 64; ++k){
            float4 b  = *(const float4*)&ws[k * 128 + c0];
            float4 a0 = *(const float4*)&xs[k * 64 + r0];
            float4 a1 = *(const float4*)&xs[k * 64 + r0 + 4];
            float ar[8] = {a0.x, a0.y, a0.z, a0.w, a1.x, a1.y, a1.z, a1.w};
            #pragma unroll
            for (int r = 0; r < 8; ++r){
                acc[r].x += ar[r] * b.x;
                acc[r].y += ar[r] * b.y;
                acc[r].z += ar[r] * b.z;
                acc[r].w += ar[r] * b.w;
            }
        }
    }

    // ---- epilogue 1: h -> bf16 ----
    #pragma unroll
    for (int r = 0; r < 8; ++r){
        size_t o = (size_t)(row0 + r0 + r) * HF + c0;
        ushort4 pk;
        pk.x = f2bf_bits(acc[r].x);
        pk.y = f2bf_bits(acc[r].y);
        pk.z = f2bf_bits(acc[r].z);
        pk.w = f2bf_bits(acc[r].w);
        *(ushort4*)(h + o) = pk;
    }

    // ---- epilogue 2: alpha dots (fp32, from registers) ----
    // cols c0..c0+3 live in one head; f = c0&31.
    float c_s[4], c_d[4];
    {
        int fb = c0 & 31;
        if (f32){
            const float* af = (const float*)av;
            #pragma unroll
            for (int j = 0; j < 4; ++j){ c_s[j] = af[fb + j]; c_d[j] = af[OUTF + fb + j]; }
        } else {
            const ushort* ab = (const ushort*)av;
            #pragma unroll
            for (int j = 0; j < 4; ++j){ c_s[j] = bf2f(ab[fb + j]); c_d[j] = bf2f(ab[OUTF + fb + j]); }
        }
    }
    int head = (tid & 31) >> 3;
    #pragma unroll
    for (int r = 0; r < 8; ++r){
        float ps = acc[r].x * c_s[0] + acc[r].y * c_s[1] + acc[r].z * c_s[2] + acc[r].w * c_s[3];
        float pd = acc[r].x * c_d[0] + acc[r].y * c_d[1] + acc[r].z * c_d[2] + acc[r].w * c_d[3];
        ps += __shfl_down(ps, 4, 8); pd += __shfl_down(pd, 4, 8);
        ps += __shfl_down(ps, 2, 8); pd += __shfl_down(pd, 2, 8);
        ps += __shfl_down(ps, 1, 8); pd += __shfl_down(pd, 1, 8);
        if ((tid & 7) == 0){
            int row = row0 + r0 + r;              // b-major over B*N
            size_t o = (size_t)row * NH + head;   // == ((b*NN+n)*NH + head)
            alpha_s[o] = ps;
            alpha_d[o] = pd;
        }
    }
}

// K2: attention weight per (b,node,head): batch softmax at last edge, /NH folded in
__global__ void k_aw(const int* __restrict__ ei, const int* __restrict__ flags,
                     const int* __restrict__ last_e,
                     const float* __restrict__ alpha_s, const float* __restrict__ alpha_d,
                     float* __restrict__ aw){
    int n = blockIdx.x * blockDim.x + threadIdx.x;
    if (n >= NN) return;
    int le = last_e[n];
    if (le < 0){
        #pragma unroll
        for (int hh = 0; hh < NH; ++hh){
            aw[((size_t)0 * NN + n) * NH + hh] = 0.f;
            aw[((size_t)1 * NN + n) * NH + hh] = 0.f;
        }
        return;
    }
    int d = get_dst(ei, le, flags[1]);
    #pragma unroll
    for (int hh = 0; hh < NH; ++hh){
        float s0 = alpha_s[((size_t)0 * NN + n) * NH + hh] + alpha_d[((size_t)0 * NN + d) * NH + hh];
        float s1 = alpha_s[((size_t)1 * NN + n) * NH + hh] + alpha_d[((size_t)1 * NN + d) * NH + hh];
        s0 = s0 > 0.f ? s0 : NEG_SLOPE * s0;
        s1 = s1 > 0.f ? s1 : NEG_SLOPE * s1;
        float m  = fmaxf(s0, s1);
        float e0 = __expf(s0 - m);
        float e1 = __expf(s1 - m);
        float inv = 1.f / (e0 + e1);
        aw[((size_t)0 * NN + n) * NH + hh] = 0.25f * e0 * inv;
        aw[((size_t)1 * NN + n) * NH + hh] = 0.25f * e1 * inv;
    }
}

// K3: edge scatter into fp32 d_out. One wave per edge; lane = b*32+f. h is bf16.
__global__ void k_scatter(const int* __restrict__ ei, const int* __restrict__ flags,
                          const ushort* __restrict__ h, const float* __restrict__ aw,
                          float* __restrict__ out_f){
    int lane = threadIdx.x & 63;
    int wid  = (blockIdx.x * blockDim.x + threadIdx.x) >> 6;
    int nw   = (gridDim.x * blockDim.x) >> 6;
    int b = lane >> 5;
    int f = lane & 31;
    int f64 = flags[1];
    for (int e = wid; e < EE; e += nw){
        int s = get_src(ei, e, f64);
        int d = get_dst(ei, e, f64);
        const float4 awv = *(const float4*)(aw + ((size_t)b * NN + s) * NH);
        const ushort* hp = h + ((size_t)b * NN + d) * HF + f;
        float acc = awv.x * bf2f(hp[0])
                  + awv.y * bf2f(hp[32])
                  + awv.z * bf2f(hp[64])
                  + awv.w * bf2f(hp[96]);
        atomicAdd(&out_f[((size_t)b * NN + s) * OUTF + f], acc);
    }
}

extern "C" void kernel_launch(void* const* d_in, const int* in_sizes, int n_in,
                              void* d_out, int out_size, void* d_ws, size_t ws_size,
                              hipStream_t stream){
    const void* x = d_in[0]; const void* eiv = d_in[1];
    const void* W = d_in[2]; const void* a  = d_in[3];
    for (int i = 0; i < n_in; ++i){
        if      (in_sizes[i] == BB * NN * INF) x   = d_in[i];
        else if (in_sizes[i] == 2 * EE)        eiv = d_in[i];
        else if (in_sizes[i] == HF * INF)      W   = d_in[i];
        else if (in_sizes[i] == 2 * OUTF)      a   = d_in[i];
    }
    const int* ei = (const int*)eiv;
    float* out = (float*)d_out;    // output dtype: float32 (verified round 3)

    // Workspace: flags | h (bf16) | alpha_s | alpha_d | aw | last_e  (~12.3 MB)
    const size_t HN = (size_t)BB * NN * HF;
    char* p = (char*)d_ws;
    int*    flags   = (int*)p;                        p += 64;
    ushort* h       = (ushort*)p;                     p += HN * 2;
    float*  alpha_s = (float*)p;                      p += (size_t)BB * NN * NH * 4;
    float*  alpha_d = (float*)p;                      p += (size_t)BB * NN * NH * 4;
    float*  aw      = (float*)p;                      p += (size_t)BB * NN * NH * 4;
    int*    last_e  = (int*)p;

    k_init   <<<(BB * NN * OUTF + 255) / 256, 256, 0, stream>>>((const ushort*)x, ei, flags, out, last_e);
    k_fused  <<<GEMM_BLOCKS + EDGE_BLOCKS, 256, 0, stream>>>(x, W, a, ei, flags, h, alpha_s, alpha_d, last_e);
    k_aw     <<<(NN + 255) / 256, 256, 0, stream>>>(ei, flags, last_e, alpha_s, alpha_d, aw);
    k_scatter<<<2048, 256, 0, stream>>>(ei, flags, h, aw, out);
}